// Round 2
// baseline (258.643 us; speedup 1.0000x reference)
//
#include <hip/hip_runtime.h>

// RNN_53214644797476: out = tanh(X @ W^T + hs @ H^T), hs never updated.
// One GEMM [32768,1024]x[1024,1024]^T (bf16 MFMA) + tiny h_term + tanh epilogue.
// GEMM uses the verified 256x256 8-phase template: BK=64, 8 waves, 128 KiB LDS,
// XOR-swizzled LDS (pre-swizzled global source + linear gload_lds dest),
// counted vmcnt, raw s_barrier, setprio around MFMA clusters.

typedef __bf16 bf16x8 __attribute__((ext_vector_type(8)));
typedef float f32x4 __attribute__((ext_vector_type(4)));
typedef unsigned short ushort8 __attribute__((ext_vector_type(8)));

constexpr int SEQ = 512, BATCH = 64;
constexpr int M_TOT = SEQ * BATCH;  // 32768
constexpr int K_D = 1024;
constexpr int N_D = 1024;

constexpr int BM = 256, BN = 256, BK = 64;
constexpr int NT = K_D / BK;          // 16 K-tiles
constexpr int HALF_ELEMS = 128 * 64;  // ushorts per half-tile (16 KiB)

__device__ __forceinline__ void async16(const void* g, void* l) {
  __builtin_amdgcn_global_load_lds(
      (const __attribute__((address_space(1))) unsigned int*)g,
      (__attribute__((address_space(3))) unsigned int*)l, 16, 0, 0);
}

__device__ __forceinline__ unsigned short f2bf(float f) {
  unsigned int u = __float_as_uint(f);
  u += 0x7FFFu + ((u >> 16) & 1u);  // round-to-nearest-even
  return (unsigned short)(u >> 16);
}

// ---- f32 -> bf16 conversion, 8 elems/thread, grid-stride ----
__global__ __launch_bounds__(256) void cvt_f32_bf16(
    const float* __restrict__ in, unsigned short* __restrict__ out, int n8) {
  int stride = gridDim.x * blockDim.x;
  for (int i = blockIdx.x * blockDim.x + threadIdx.x; i < n8; i += stride) {
    const float4* p = reinterpret_cast<const float4*>(in + (size_t)i * 8);
    float4 a = p[0], b = p[1];
    ushort8 v;
    v[0] = f2bf(a.x); v[1] = f2bf(a.y); v[2] = f2bf(a.z); v[3] = f2bf(a.w);
    v[4] = f2bf(b.x); v[5] = f2bf(b.y); v[6] = f2bf(b.z); v[7] = f2bf(b.w);
    *reinterpret_cast<ushort8*>(out + (size_t)i * 8) = v;
  }
}

// ---- h_term[b][h] = sum_k hs[b][k] * H[h][k] ; one block per h ----
__global__ __launch_bounds__(256) void hterm_kernel(
    const float* __restrict__ hs, const float* __restrict__ Hm,
    float* __restrict__ ht) {
  int h = blockIdx.x;
  __shared__ float Hrow[1024];
  for (int i = threadIdx.x; i < 1024; i += 256)
    Hrow[i] = Hm[(size_t)h * 1024 + i];
  __syncthreads();
  int w = threadIdx.x >> 6, l = threadIdx.x & 63;
  for (int b = w; b < 64; b += 4) {
    float s = 0.f;
    const float* hb = hs + (size_t)b * 1024;
    for (int k = l; k < 1024; k += 64) s += hb[k] * Hrow[k];
#pragma unroll
    for (int off = 32; off > 0; off >>= 1) s += __shfl_down(s, off, 64);
    if (l == 0) ht[b * 1024 + h] = s;
  }
}

// Stage one 128x64 bf16 half-tile: linear LDS dest (gload_lds requirement),
// global source pre-permuted so stored slot s' holds logical slot s'^(row&7).
__device__ __forceinline__ void stage_half(const unsigned short* __restrict__ g,
                                           int rowbase, int kbase,
                                           unsigned short* lh, int tid) {
#pragma unroll
  for (int i = 0; i < 2; ++i) {
    int c = tid + i * 512;          // chunk 0..1023
    int r = c >> 3;                 // row in half-tile
    int s = (c & 7) ^ (r & 7);      // logical 16B slot for this stored slot
    async16(g + (size_t)(rowbase + r) * 1024 + kbase + s * 8, lh + c * 8);
  }
}

// ---- main GEMM: C = tanh(A[M,K] . B[N,K]^T + ht[m%64][n]) ----
__global__ __launch_bounds__(512, 2) void gemm_tanh(
    const unsigned short* __restrict__ A, const unsigned short* __restrict__ B,
    const float* __restrict__ ht, float* __restrict__ out0,
    float* __restrict__ out1) {
  __shared__ unsigned short As[4 * HALF_ELEMS];  // [buf(2)][half(2)] 64 KiB
  __shared__ unsigned short Bs[4 * HALF_ELEMS];  // 64 KiB

  // XCD-bijective swizzle (nwg = 512, divisible by 8); bm-contiguous per XCD.
  int bid = blockIdx.x;
  int swz = (bid & 7) * 64 + (bid >> 3);
  int bm = swz >> 2;  // 0..127
  int bn = swz & 3;   // 0..3

  int tid = threadIdx.x;
  int lane = tid & 63, wid = tid >> 6;
  int wr = wid >> 2, wc = wid & 3;  // 2 x 4 waves; per-wave 128x64 output
  int fr = lane & 15, kq = lane >> 4, f7 = fr & 7;

  f32x4 acc[8][4] = {};
  bf16x8 bg[4][2];

  // Prologue: K-tile 0 (A0,A1,B0,B1) + K-tile 1's B halves.
  stage_half(A, bm * BM + 0,   0, As + 0 * HALF_ELEMS, tid);
  stage_half(A, bm * BM + 128, 0, As + 1 * HALF_ELEMS, tid);
  stage_half(B, bn * BN + 0,   0, Bs + 0 * HALF_ELEMS, tid);
  stage_half(B, bn * BN + 128, 0, Bs + 1 * HALF_ELEMS, tid);
  stage_half(B, bn * BN + 0,   BK, Bs + 2 * HALF_ELEMS, tid);
  stage_half(B, bn * BN + 128, BK, Bs + 3 * HALF_ELEMS, tid);
  asm volatile("s_waitcnt vmcnt(4)" ::: "memory");  // drain K-tile 0's 4 halves
  __builtin_amdgcn_s_barrier();

  for (int kt = 0; kt < NT; ++kt) {
    const int bi = kt & 1;
    const unsigned short* Ab = As + (bi * 2 + wr) * HALF_ELEMS;
    const unsigned short* Bb = Bs + (bi * 2 + (wc >> 1)) * HALF_ELEMS;
    const int brow0 = (wc & 1) * 64;

#pragma unroll
    for (int q = 0; q < 4; ++q) {
      bf16x8 af[2][2];
      if (q == 0) {
#pragma unroll
        for (int ni = 0; ni < 4; ++ni)
#pragma unroll
          for (int kk = 0; kk < 2; ++kk) {
            int rb = brow0 + ni * 16 + fr;
            bg[ni][kk] = *reinterpret_cast<const bf16x8*>(
                &Bb[rb * 64 + ((kk * 4 + kq) ^ f7) * 8]);
          }
      }
#pragma unroll
      for (int dm = 0; dm < 2; ++dm)
#pragma unroll
        for (int kk = 0; kk < 2; ++kk) {
          int ra = (q * 2 + dm) * 16 + fr;
          af[dm][kk] = *reinterpret_cast<const bf16x8*>(
              &Ab[ra * 64 + ((kk * 4 + kq) ^ f7) * 8]);
        }
      // Stage one half-tile per phase. A(kt+1) -> opposite buffer (free since
      // kt-1 finished); B(kt+2) -> this buffer (its reads ended at phase 0).
      if (q == 0 && kt + 1 < NT)
        stage_half(A, bm * BM + 0,   (kt + 1) * BK,
                   As + ((bi ^ 1) * 2 + 0) * HALF_ELEMS, tid);
      if (q == 1 && kt + 1 < NT)
        stage_half(A, bm * BM + 128, (kt + 1) * BK,
                   As + ((bi ^ 1) * 2 + 1) * HALF_ELEMS, tid);
      if (q == 2 && kt + 2 < NT)
        stage_half(B, bn * BN + 0,   (kt + 2) * BK,
                   Bs + (bi * 2 + 0) * HALF_ELEMS, tid);
      if (q == 3 && kt + 2 < NT)
        stage_half(B, bn * BN + 128, (kt + 2) * BK,
                   Bs + (bi * 2 + 1) * HALF_ELEMS, tid);

      __builtin_amdgcn_s_barrier();
      asm volatile("s_waitcnt lgkmcnt(0)" ::: "memory");
      __builtin_amdgcn_s_setprio(1);
#pragma unroll
      for (int dm = 0; dm < 2; ++dm)
#pragma unroll
        for (int ni = 0; ni < 4; ++ni)
#pragma unroll
          for (int kk = 0; kk < 2; ++kk)
            acc[q * 2 + dm][ni] = __builtin_amdgcn_mfma_f32_16x16x32_bf16(
                af[dm][kk], bg[ni][kk], acc[q * 2 + dm][ni], 0, 0, 0);
      __builtin_amdgcn_s_setprio(0);
      if (q == 3) {
        // Counted drain, once per K-tile: leaves B(kt+2)'s 2 halves (4 loads)
        // in flight; guarantees A(kt+1),B(kt+1) resident for next K-tile.
        if (kt < NT - 2)
          asm volatile("s_waitcnt vmcnt(4)" ::: "memory");
        else if (kt == NT - 2)
          asm volatile("s_waitcnt vmcnt(0)" ::: "memory");
      }
      __builtin_amdgcn_s_barrier();
    }
  }

  // Epilogue: y = tanh(acc + ht[m%64][n]); out0 always, out1 for last 64 rows.
  const int nbase = bn * BN + wc * 64;
  const int mbase = bm * BM + wr * 128;
#pragma unroll
  for (int mi = 0; mi < 8; ++mi) {
#pragma unroll
    for (int r = 0; r < 4; ++r) {
      int m = mbase + mi * 16 + kq * 4 + r;
      int b = m & 63;
#pragma unroll
      for (int ni = 0; ni < 4; ++ni) {
        int n = nbase + ni * 16 + fr;
        float x = acc[mi][ni][r] + ht[b * 1024 + n];
        float e = __expf(2.0f * x);
        float y = 1.0f - 2.0f / (e + 1.0f);  // tanh(x), safe at +-inf
        out0[(size_t)m * 1024 + n] = y;
        if (m >= M_TOT - 64) out1[(m - (M_TOT - 64)) * 1024 + n] = y;
      }
    }
  }
}

extern "C" void kernel_launch(void* const* d_in, const int* in_sizes, int n_in,
                              void* d_out, int out_size, void* d_ws,
                              size_t ws_size, hipStream_t stream) {
  (void)in_sizes; (void)n_in; (void)out_size; (void)ws_size;
  const float* X  = (const float*)d_in[0];  // [512,64,1024]
  const float* hs = (const float*)d_in[1];  // [64,1024]
  const float* W  = (const float*)d_in[2];  // [1024,1024]
  const float* Hm = (const float*)d_in[3];  // [1024,1024]
  float* out0 = (float*)d_out;               // [32768,1024]
  float* out1 = out0 + (size_t)M_TOT * N_D;  // [64,1024]

  // ws layout: Xbf (64 MiB) | Wbf (2 MiB) | hterm (256 KiB)
  unsigned short* Xbf = (unsigned short*)d_ws;
  unsigned short* Wbf = Xbf + (size_t)M_TOT * K_D;
  float* hterm = (float*)(Wbf + (size_t)N_D * K_D);

  cvt_f32_bf16<<<2048, 256, 0, stream>>>(X, Xbf, M_TOT * K_D / 8);
  cvt_f32_bf16<<<512, 256, 0, stream>>>(W, Wbf, N_D * K_D / 8);
  hterm_kernel<<<1024, 256, 0, stream>>>(hs, Hm, hterm);
  gemm_tanh<<<(M_TOT / BM) * (N_D / BN), 512, 0, stream>>>(Xbf, Wbf, hterm,
                                                           out0, out1);
}

// Round 3
// 245.253 us; speedup vs baseline: 1.0546x; 1.0546x over previous
//
#include <hip/hip_runtime.h>

// RNN_53214644797476: out = tanh(X @ W^T + hs @ H^T), hs never updated.
// => one GEMM [32768,1024]x[1024,1024]^T + tiny h_term + tanh epilogue.
// Round 3: fuse the X f32->bf16 conversion INTO the GEMM's A-staging
// (reg-stage + cvt + swizzled ds_write). B (W, 2 MiB) stays pre-converted
// and staged via global_load_lds with pre-swizzled source. 128x128 tile,
// BK=32, 4 waves, LDS double-buffer (32 KiB -> 3 blocks/CU), 1 barrier +
// counted vmcnt per K-tile. XOR swizzle g(r)=(r>>1)&3 on 4-slot rows
// (conflict-free reads AND writes, verified by bank arithmetic).

typedef __bf16 bf16x8 __attribute__((ext_vector_type(8)));
typedef float f32x4 __attribute__((ext_vector_type(4)));
typedef unsigned short ushort8 __attribute__((ext_vector_type(8)));

constexpr int M_TOT = 32768;  // SEQ*BATCH
constexpr int K_D = 1024;
constexpr int N_D = 1024;
constexpr int NTK = K_D / 32;  // 32 K-tiles of BK=32

__device__ __forceinline__ void async16(const void* g, void* l) {
  __builtin_amdgcn_global_load_lds(
      (const __attribute__((address_space(1))) unsigned int*)g,
      (__attribute__((address_space(3))) unsigned int*)l, 16, 0, 0);
}

__device__ __forceinline__ unsigned short f2bf(float f) {
  unsigned int u = __float_as_uint(f);
  u += 0x7FFFu + ((u >> 16) & 1u);  // round-to-nearest-even
  return (unsigned short)(u >> 16);
}

// ---- f32 -> bf16 conversion (W only, 2 MiB) ----
__global__ __launch_bounds__(256) void cvt_f32_bf16(
    const float* __restrict__ in, unsigned short* __restrict__ out, int n8) {
  int stride = gridDim.x * blockDim.x;
  for (int i = blockIdx.x * blockDim.x + threadIdx.x; i < n8; i += stride) {
    const float4* p = reinterpret_cast<const float4*>(in + (size_t)i * 8);
    float4 a = p[0], b = p[1];
    ushort8 v;
    v[0] = f2bf(a.x); v[1] = f2bf(a.y); v[2] = f2bf(a.z); v[3] = f2bf(a.w);
    v[4] = f2bf(b.x); v[5] = f2bf(b.y); v[6] = f2bf(b.z); v[7] = f2bf(b.w);
    *reinterpret_cast<ushort8*>(out + (size_t)i * 8) = v;
  }
}

// ---- h_term[b][h] = sum_k hs[b][k] * H[h][k] ; one block per h ----
__global__ __launch_bounds__(256) void hterm_kernel(
    const float* __restrict__ hs, const float* __restrict__ Hm,
    float* __restrict__ ht) {
  int h = blockIdx.x;
  __shared__ float Hrow[1024];
  for (int i = threadIdx.x; i < 1024; i += 256)
    Hrow[i] = Hm[(size_t)h * 1024 + i];
  __syncthreads();
  int w = threadIdx.x >> 6, l = threadIdx.x & 63;
  for (int b = w; b < 64; b += 4) {
    float s = 0.f;
    const float* hb = hs + (size_t)b * 1024;
    for (int k = l; k < 1024; k += 64) s += hb[k] * Hrow[k];
#pragma unroll
    for (int off = 32; off > 0; off >>= 1) s += __shfl_down(s, off, 64);
    if (l == 0) ht[b * 1024 + h] = s;
  }
}

// ---- fused GEMM: C = tanh(X_f32[M,K] . Wbf[N,K]^T + ht[m%64][n]) ----
// Chunk c in [0,1024): LDS offset c*8 ushorts = row (c>>2), stored slot (c&3).
// Stored slot s' holds logical slot s = s' ^ g(r), g(r) = (r>>1)&3.
__global__ __launch_bounds__(256, 3) void gemm_fused(
    const float* __restrict__ X, const unsigned short* __restrict__ Wb,
    const float* __restrict__ ht, float* __restrict__ out0,
    float* __restrict__ out1) {
  __shared__ unsigned short As[2][128 * 32];
  __shared__ unsigned short Bs[2][128 * 32];

  // XCD-bijective swizzle (nwg = 2048): all 8 bn-sharers of an A-panel land
  // on the same XCD -> X fetched from HBM ~once.
  int bid = blockIdx.x;
  int swz = (bid & 7) * 256 + (bid >> 3);
  int bm = swz >> 3;  // 0..255
  int bn = swz & 7;   // 0..7

  int tid = threadIdx.x;
  int lane = tid & 63, wid = tid >> 6;
  int wr = wid >> 1, wc = wid & 1;
  int fr = lane & 15, kq = lane >> 4;

  // Two staging chunks per thread.
  int c0 = tid, c1 = tid + 256;
  int r0 = c0 >> 2, s0 = (c0 & 3) ^ ((c0 >> 3) & 3);
  int r1 = c1 >> 2, s1 = (c1 & 3) ^ ((c1 >> 3) & 3);
  const float* gA0 = X + (size_t)(bm * 128 + r0) * 1024 + s0 * 8;
  const float* gA1 = X + (size_t)(bm * 128 + r1) * 1024 + s1 * 8;
  const unsigned short* gB0 = Wb + (size_t)(bn * 128 + r0) * 1024 + s0 * 8;
  const unsigned short* gB1 = Wb + (size_t)(bn * 128 + r1) * 1024 + s1 * 8;

  f32x4 acc[4][4] = {};
  float4 a0, a1, a2, a3;  // in-flight A chunk data (static names, rule #20)

#define LOAD_A(kt)                                                        \
  {                                                                       \
    const float4* p0 = reinterpret_cast<const float4*>(gA0 + (kt) * 32);  \
    const float4* p1 = reinterpret_cast<const float4*>(gA1 + (kt) * 32);  \
    a0 = p0[0]; a1 = p0[1]; a2 = p1[0]; a3 = p1[1];                       \
  }
#define WRITE_A(buf)                                                      \
  {                                                                       \
    ushort8 v;                                                            \
    v[0] = f2bf(a0.x); v[1] = f2bf(a0.y); v[2] = f2bf(a0.z);              \
    v[3] = f2bf(a0.w); v[4] = f2bf(a1.x); v[5] = f2bf(a1.y);              \
    v[6] = f2bf(a1.z); v[7] = f2bf(a1.w);                                 \
    *reinterpret_cast<ushort8*>(&As[buf][c0 * 8]) = v;                    \
    v[0] = f2bf(a2.x); v[1] = f2bf(a2.y); v[2] = f2bf(a2.z);              \
    v[3] = f2bf(a2.w); v[4] = f2bf(a3.x); v[5] = f2bf(a3.y);              \
    v[6] = f2bf(a3.z); v[7] = f2bf(a3.w);                                 \
    *reinterpret_cast<ushort8*>(&As[buf][c1 * 8]) = v;                    \
  }
#define STAGE_B(kt, buf)                          \
  {                                               \
    async16(gB0 + (kt) * 32, &Bs[buf][c0 * 8]);   \
    async16(gB1 + (kt) * 32, &Bs[buf][c1 * 8]);   \
  }

  // Prologue: A(0) regs + B(0) lds; write A(0); issue A(1); drain B(0).
  LOAD_A(0);
  STAGE_B(0, 0);
  WRITE_A(0);
  LOAD_A(1);
  asm volatile("s_waitcnt vmcnt(4) lgkmcnt(0)" ::: "memory");
  __builtin_amdgcn_s_barrier();
  asm volatile("" ::: "memory");  // fence: no LDS reads hoist above barrier

  for (int kt = 0; kt < NTK; ++kt) {
    const int cur = kt & 1;
    if (kt + 1 < NTK) STAGE_B(kt + 1, cur ^ 1);

    bf16x8 af[4], bg[4];
#pragma unroll
    for (int mi = 0; mi < 4; ++mi) {
      int ra = wr * 64 + mi * 16 + fr;
      af[mi] = *reinterpret_cast<const bf16x8*>(
          &As[cur][ra * 32 + ((kq ^ ((ra >> 1) & 3))) * 8]);
    }
#pragma unroll
    for (int ni = 0; ni < 4; ++ni) {
      int rb = wc * 64 + ni * 16 + fr;
      bg[ni] = *reinterpret_cast<const bf16x8*>(
          &Bs[cur][rb * 32 + ((kq ^ ((rb >> 1) & 3))) * 8]);
    }
#pragma unroll
    for (int mi = 0; mi < 4; ++mi)
#pragma unroll
      for (int ni = 0; ni < 4; ++ni)
        acc[mi][ni] = __builtin_amdgcn_mfma_f32_16x16x32_bf16(
            af[mi], bg[ni], acc[mi][ni], 0, 0, 0);

    if (kt + 1 < NTK) {
      WRITE_A(cur ^ 1);  // compiler auto-waits a0..a3 (vmcnt leaves B in flight)
      if (kt + 2 < NTK) {
        LOAD_A(kt + 2);
        // drain B(kt+1) (2 gloads); keep A(kt+2)'s 4 loads in flight
        asm volatile("s_waitcnt vmcnt(4) lgkmcnt(0)" ::: "memory");
      } else {
        asm volatile("s_waitcnt vmcnt(0) lgkmcnt(0)" ::: "memory");
      }
      __builtin_amdgcn_s_barrier();
      asm volatile("" ::: "memory");
    }
  }

  // Epilogue: y = tanh(acc + ht[m%64][n]); out0 always, out1 for last 64 rows.
  const int nbase = bn * 128 + wc * 64;
#pragma unroll
  for (int mi = 0; mi < 4; ++mi) {
#pragma unroll
    for (int r = 0; r < 4; ++r) {
      int mloc = wr * 64 + mi * 16 + kq * 4 + r;
      size_t m = (size_t)bm * 128 + mloc;
      int b = mloc & 63;
#pragma unroll
      for (int ni = 0; ni < 4; ++ni) {
        int n = nbase + ni * 16 + fr;
        float x = acc[mi][ni][r] + ht[b * 1024 + n];
        float e = __expf(2.0f * x);
        float y = 1.0f - 2.0f / (e + 1.0f);  // tanh(x), safe at +-inf
        out0[m * 1024 + n] = y;
        if (m >= (size_t)(M_TOT - 64))
          out1[(m - (M_TOT - 64)) * 1024 + n] = y;
      }
    }
  }
#undef LOAD_A
#undef WRITE_A
#undef STAGE_B
}

extern "C" void kernel_launch(void* const* d_in, const int* in_sizes, int n_in,
                              void* d_out, int out_size, void* d_ws,
                              size_t ws_size, hipStream_t stream) {
  (void)in_sizes; (void)n_in; (void)out_size; (void)ws_size;
  const float* X  = (const float*)d_in[0];  // [512,64,1024] = [32768,1024]
  const float* hs = (const float*)d_in[1];  // [64,1024]
  const float* W  = (const float*)d_in[2];  // [1024,1024]
  const float* Hm = (const float*)d_in[3];  // [1024,1024]
  float* out0 = (float*)d_out;               // [32768,1024]
  float* out1 = out0 + (size_t)M_TOT * N_D;  // [64,1024]

  // ws layout: Wbf (2 MiB) | hterm (256 KiB)
  unsigned short* Wbf = (unsigned short*)d_ws;
  float* hterm = (float*)(Wbf + (size_t)N_D * K_D);

  cvt_f32_bf16<<<512, 256, 0, stream>>>(W, Wbf, N_D * K_D / 8);
  hterm_kernel<<<1024, 256, 0, stream>>>(hs, Hm, hterm);
  gemm_fused<<<2048, 256, 0, stream>>>(X, Wbf, hterm, out0, out1);
}